// Round 22
// baseline (201.030 us; speedup 1.0000x reference)
//
#include <hip/hip_runtime.h>
#include <hip/hip_bf16.h>

typedef __bf16  v8bf __attribute__((ext_vector_type(8)));
typedef float   v4f  __attribute__((ext_vector_type(4)));
typedef float   f4   __attribute__((ext_vector_type(4)));
typedef unsigned short us8 __attribute__((ext_vector_type(8)));
typedef unsigned short us4 __attribute__((ext_vector_type(4)));
typedef unsigned int u32;

#define BATCH 32
#define CDIM  256
#define HW    1024

// ---- shared ws offsets (bytes) -------------------------------------------
#define OFF_HBT 0L
#define OFF_MBT (OFF_HBT + 16777216L)   // m_bfT
#define OFF_QKH (OFF_MBT + 16777216L)   // qk_h  [32][1024][256]
#define OFF_QKM (OFF_QKH + 16777216L)   // k2_m  [32][1024][128]
#define OFF_VH  (OFF_QKM + 8388608L)    // v_h   [32][256][1024]
#define OFF_VM  (OFF_VH  + 16777216L)   // v_m
#define OFF_ZCT (OFF_VM  + 16777216L)   // zcatT [32][1024][512]
#define OFF_W   (OFF_ZCT + 33554432L)   // weights (1933312 shorts)
#define OFF_B   (OFF_W   + 3866624L)    // biases (2944 floats)
#define WS_TOTAL (OFF_B + 2944L * 4)
// weight sub-offsets (shorts from OFF_W)
#define W_QK  0
#define W_K2  65536
#define W_V   98304
#define W_V2  163840
#define W_M   491520
#define W_ZT  1081344
#define W_F   1343488
// bias sub-offsets (floats from OFF_B)
#define B_QK  0
#define B_K2  256
#define B_V   384
#define B_V2  640
#define B_F   2176

__device__ inline unsigned short f2u(float x) {
    __hip_bfloat16 h = __float2bfloat16(x);
    union { __hip_bfloat16 h; unsigned short u; } cv; cv.h = h; return cv.u;
}
__device__ inline float u2f(unsigned short u) {
    union { unsigned short u; __hip_bfloat16 h; } cv; cv.u = u; return __bfloat162float(cv.h);
}
__device__ inline float sigmoidf_(float x) {
    x = fminf(fmaxf(x, -30.f), 30.f);
    return 1.f / (1.f + __expf(-x));
}
__device__ inline float tanhf_(float x) {
    x = fminf(fmaxf(x, -15.f), 15.f);
    float e = __expf(2.f * x);
    return (e - 1.f) / (e + 1.f);
}
// direct global->LDS DMA, 16B per lane; lds dest is wave-uniform base + lane*16
__device__ inline void glds16(const unsigned short* g, unsigned short* l) {
    __builtin_amdgcn_global_load_lds(
        (const __attribute__((address_space(1))) u32*)g,
        (__attribute__((address_space(3))) u32*)l, 16, 0, 0);
}

// ---------------------------------------------------------------------------
// prep: weight pack (blocks 0..6024) + bias fold (6025..6027) +
//       transposing fp32->bf16 convert of h,m (6028..10123).
// ---------------------------------------------------------------------------
__global__ __launch_bounds__(256)
void prep(const float* __restrict__ hsrc, const float* __restrict__ msrc,
          const float* __restrict__ Wq, const float* __restrict__ Wk,
          const float* __restrict__ Wv, const float* __restrict__ Wk2,
          const float* __restrict__ Wv2, const float* __restrict__ Wz,
          const float* __restrict__ Wm,
          const float* __restrict__ bq, const float* __restrict__ bk,
          const float* __restrict__ bk2, const float* __restrict__ bv,
          const float* __restrict__ bv2, const float* __restrict__ bz,
          const float* __restrict__ bm,
          char* __restrict__ ws)
{
    __shared__ float t[64][68];
    unsigned short* wdst = (unsigned short*)(ws + OFF_W);
    float*          bdst = (float*)(ws + OFF_B);
    const int bid = blockIdx.x;
    const int tid = threadIdx.x;

    if (bid < 6025) {                       // ---- weight pack
        const int gid = bid * 256 + tid;
        if (gid < 1081344) {
            const float* s; int off;
            if      (gid <   32768) { s = Wq;  off = gid; }
            else if (gid <   65536) { s = Wk;  off = gid -   32768; }
            else if (gid <   98304) { s = Wk2; off = gid -   65536; }
            else if (gid <  163840) { s = Wv;  off = gid -   98304; }
            else if (gid <  229376) { s = Wv2; off = gid -  163840; }
            else if (gid <  491520) { s = Wz;  off = gid -  229376; }
            else                    { s = Wm;  off = gid -  491520; }
            wdst[gid] = f2u(s[off]);
        } else if (gid < 1343488) {
            const int idx = gid - 1081344;          // WzT[k][j] = Wz[j][k]
            const int k = idx >> 9, j = idx & 511;
            wdst[gid] = f2u(Wz[j * 512 + k]);
        } else if (gid < 1540096) {
            const int idx = gid - 1343488;          // Wf[o][512+r] = Wm[o][512+r]
            const int o = idx >> 8, kk = 512 + (idx & 255);
            wdst[W_F + o * 768 + kk] = f2u(Wm[o * 768 + kk]);
        } else {
            const int bi = gid - 1540096;
            if (bi < 2176) {
                const float* s; int off;
                if      (bi <  128) { s = bq;  off = bi; }
                else if (bi <  256) { s = bk;  off = bi -  128; }
                else if (bi <  384) { s = bk2; off = bi -  256; }
                else if (bi <  640) { s = bv;  off = bi -  384; }
                else if (bi <  896) { s = bv2; off = bi -  640; }
                else if (bi < 1408) { s = bz;  off = bi -  896; }
                else                { s = bm;  off = bi - 1408; }
                bdst[bi] = s[off];
            }
        }
    } else if (bid < 6028) {                // ---- bfused = bm + Wm[:, :512] @ bz
        const int o = (bid - 6025) * 256 + tid;
        if (o < 768) {
            float s = bm[o];
            const float* r = Wm + (long)o * 768;
#pragma unroll 8
            for (int j = 0; j < 512; ++j) s += r[j] * bz[j];
            bdst[B_F + o] = s;
        }
    } else {                                // ---- transpose_cvt
        const int tz = bid - 6028;          // 0..4095
        const int z  = tz >> 6;             // 0..63
        const int p0 = (tz & 15) * 64;
        const int c0 = ((tz >> 4) & 3) * 64;
        const float* src = (z < BATCH) ? hsrc + (long)z * CDIM * HW
                                       : msrc + (long)(z - BATCH) * CDIM * HW;
        unsigned short* dst = (unsigned short*)(ws + ((z < BATCH) ? OFF_HBT : OFF_MBT))
                              + (long)((z < BATCH) ? z : z - BATCH) * HW * CDIM;
        const int r  = tid >> 4;
        const int c4 = (tid & 15) * 4;
#pragma unroll
        for (int i = 0; i < 4; ++i) {
            const f4 v = *reinterpret_cast<const f4*>(src + (long)(c0 + r + 16 * i) * HW + p0 + c4);
            t[r + 16 * i][c4 + 0] = v[0];
            t[r + 16 * i][c4 + 1] = v[1];
            t[r + 16 * i][c4 + 2] = v[2];
            t[r + 16 * i][c4 + 3] = v[3];
        }
        __syncthreads();
#pragma unroll
        for (int i = 0; i < 4; ++i) {
            const int pr = r + 16 * i;
            us4 o;
#pragma unroll
            for (int j = 0; j < 4; ++j) o[j] = f2u(t[c4 + j][pr]);
            *reinterpret_cast<us4*>(dst + (long)(p0 + pr) * CDIM + c0 + c4) = o;
        }
    }
}

// ---------------------------------------------------------------------------
// Shared GEMM core v3 (R20): 128x128 tile, BK=64, st-swizzled LDS, A/B
// double-buffered, ONE barrier per K-tile, staging interleaved into compute.
// smem = 32768 shorts (64KB); Cs bounce overlays smem in the epilogue.
// ---------------------------------------------------------------------------
__device__ __forceinline__
void gemm_core(const unsigned short* __restrict__ A, int lda,
               const unsigned short* __restrict__ A2, int lda2, int kswitch,
               const unsigned short* __restrict__ Bt, int ldb,
               unsigned short* __restrict__ Cp, int ldc,
               int K, const float* __restrict__ bias, int biasMode,
               int m0, int n0,
               unsigned short* smem)
{
    const int tid  = threadIdx.x;
    const int lane = tid & 63;
    const int w    = tid >> 6;

    v4f acc[4][4];
#pragma unroll
    for (int i = 0; i < 4; ++i)
#pragma unroll
        for (int j = 0; j < 4; ++j) acc[i][j] = v4f{0.f, 0.f, 0.f, 0.f};

    const int wm   = (w >> 1) * 64;
    const int wn   = (w & 1) * 64;
    const int fr   = lane & 15;
    const int g    = lane >> 4;

    const int arow = (w << 3) + (lane >> 3);
    const int acol = (((lane & 7) ^ ((lane >> 3) & 7)) * 8);
    const int lbase = (w << 9);

    const int nt = K >> 6;

#define GSTAGE_A(t, bi, i)                                                     \
    { const int k0 = (t) * 64;                                                 \
      const unsigned short* Ab; int Al; int Ao;                                \
      if (k0 < kswitch) { Ab = A;  Al = lda;  Ao = k0; }                       \
      else              { Ab = A2; Al = lda2; Ao = k0 - kswitch; }             \
      glds16(Ab + (long)(m0 + (i) * 32 + arow) * Al + Ao + acol,               \
             &smem[(bi) * 8192 + (i) * 2048 + lbase]); }
#define GSTAGE_B(t, bi, i)                                                     \
    { const int k0 = (t) * 64;                                                 \
      glds16(Bt + (long)(n0 + (i) * 32 + arow) * ldb + k0 + acol,              \
             &smem[16384 + (bi) * 8192 + (i) * 2048 + lbase]); }

    // prologue: stage tile 0 -> buf 0
#pragma unroll
    for (int i = 0; i < 4; ++i) { GSTAGE_A(0, 0, i); GSTAGE_B(0, 0, i); }

    for (int t = 0; t < nt; ++t) {
        __syncthreads();   // implicit vmcnt(0): tile t landed; reads of buf[(t+1)&1] done

        const unsigned short* Ar = smem + (t & 1) * 8192;
        const unsigned short* Br = smem + 16384 + (t & 1) * 8192;
        const int nb = (t + 1) & 1;
        const bool more = (t + 1 < nt);

#pragma unroll
        for (int ks = 0; ks < 2; ++ks) {
            const int slot = ((ks * 4 + g) ^ (fr & 7)) * 8;
            v8bf af[4], bfv[4];
#pragma unroll
            for (int mi = 0; mi < 4; ++mi)
                af[mi] = *reinterpret_cast<const v8bf*>(&Ar[(wm + mi * 16 + fr) * 64 + slot]);
#pragma unroll
            for (int ni = 0; ni < 4; ++ni)
                bfv[ni] = *reinterpret_cast<const v8bf*>(&Br[(wn + ni * 16 + fr) * 64 + slot]);
            // interleave next-tile staging with this phase's MFMAs
            if (more) {
                if (ks == 0) { GSTAGE_A(t + 1, nb, 0); GSTAGE_A(t + 1, nb, 1);
                               GSTAGE_A(t + 1, nb, 2); GSTAGE_A(t + 1, nb, 3); }
                else         { GSTAGE_B(t + 1, nb, 0); GSTAGE_B(t + 1, nb, 1);
                               GSTAGE_B(t + 1, nb, 2); GSTAGE_B(t + 1, nb, 3); }
            }
            __builtin_amdgcn_s_setprio(1);
#pragma unroll
            for (int mi = 0; mi < 4; ++mi)
#pragma unroll
                for (int ni = 0; ni < 4; ++ni)
                    acc[mi][ni] = __builtin_amdgcn_mfma_f32_16x16x32_bf16(af[mi], bfv[ni], acc[mi][ni], 0, 0, 0);
            __builtin_amdgcn_s_setprio(0);
        }
    }
#undef GSTAGE_A
#undef GSTAGE_B

    __syncthreads();   // last tile's LDS reads done; smem reusable as Cs

    // ---- epilogue: acc+bias -> Cs[128][132] bf16, then coalesced us8 stores
    unsigned short* Cs = smem;
#pragma unroll
    for (int mi = 0; mi < 4; ++mi) {
#pragma unroll
        for (int ni = 0; ni < 4; ++ni) {
            const int col = wn + ni * 16 + fr;
            const int rb  = wm + mi * 16 + g * 4;
            const float bn = (biasMode == 1) ? bias[n0 + col] : 0.f;
#pragma unroll
            for (int r = 0; r < 4; ++r) {
                float x = acc[mi][ni][r] + bn;
                if (biasMode == 2) x += bias[m0 + rb + r];
                Cs[(rb + r) * 132 + col] = f2u(x);
            }
        }
    }
    __syncthreads();

    const int orow = tid >> 4;          // 0..15
    const int och  = (tid & 15) * 8;    // 0..120
#pragma unroll
    for (int i = 0; i < 8; ++i) {
        const int row = i * 16 + orow;
        *reinterpret_cast<us8*>(Cp + (long)(m0 + row) * ldc + n0 + och) =
            *reinterpret_cast<const us8*>(&Cs[row * 132 + och]);
    }
}

// 5 GEMM jobs in one dispatch (1816 blocks), XCD-locality swizzled (R21:
// consecutive job ids per XCD -> same-batch panels L2-resident; fixed the
// L3-bound staging that pinned 3 different schedules at ~76us).
__global__ __launch_bounds__(256)
void gemm_multi(char* __restrict__ ws)
{
    __shared__ unsigned short smem[32768];   // 64 KB: A/B dbuf + Cs bounce
    unsigned short* wA = (unsigned short*)(ws + OFF_W);
    float*          bA = (float*)(ws + OFF_B);
    const int raw = blockIdx.x;
    const int id  = (raw & 7) * 227 + (raw >> 3);   // bijective: 1816 = 8*227

    if (id < 512) {
        const int b = id >> 4, x = id & 7, y = (id >> 3) & 1;
        const unsigned short* A = (unsigned short*)(ws + OFF_HBT) + (long)b * 262144;
        gemm_core(A, 256, A, 256, 1 << 30, wA + W_QK, 256,
                  (unsigned short*)(ws + OFF_QKH) + (long)b * 262144, 256,
                  256, bA + B_QK, 1, x * 128, y * 128, smem);
    } else if (id < 768) {
        const int idx = id - 512, b = idx >> 3, x = idx & 7;
        const unsigned short* A = (unsigned short*)(ws + OFF_MBT) + (long)b * 262144;
        gemm_core(A, 256, A, 256, 1 << 30, wA + W_K2, 256,
                  (unsigned short*)(ws + OFF_QKM) + (long)b * 131072, 128,
                  256, bA + B_K2, 1, x * 128, 0, smem);
    } else if (id < 1280) {
        const int idx = id - 768, b = idx >> 4, x = idx & 1, y = (idx >> 1) & 7;
        gemm_core(wA + W_V, 256, wA + W_V, 256, 1 << 30,
                  (unsigned short*)(ws + OFF_HBT) + (long)b * 262144, 256,
                  (unsigned short*)(ws + OFF_VH) + (long)b * 262144, 1024,
                  256, bA + B_V, 2, x * 128, y * 128, smem);
    } else if (id < 1792) {
        const int idx = id - 1280, b = idx >> 4, x = idx & 1, y = (idx >> 1) & 7;
        gemm_core(wA + W_V2, 256, wA + W_V2, 256, 1 << 30,
                  (unsigned short*)(ws + OFF_MBT) + (long)b * 262144, 256,
                  (unsigned short*)(ws + OFF_VM) + (long)b * 262144, 1024,
                  256, bA + B_V2, 2, x * 128, y * 128, smem);
    } else {
        const int idx = id - 1792, x = idx % 6, y = idx / 6;
        gemm_core(wA + W_M, 768, wA + W_M, 768, 1 << 30, wA + W_ZT, 512,
                  wA + W_F, 768, 512, bA, 0, x * 128, y * 128, smem);
    }
}

// ---------------------------------------------------------------------------
// comb_gemm v4 + FUSED GATING (R16, passed): 256-row x 3x64-col gather, one
// barrier per K-tile, staging interleaved into compute phases.
// ---------------------------------------------------------------------------
__global__ __launch_bounds__(512, 2)
void comb_gemm(const unsigned short* __restrict__ A, int lda,
               const unsigned short* __restrict__ A2, int lda2, int kswitch,
               const unsigned short* __restrict__ Bt, int ldb,
               int K, const float* __restrict__ bias,
               const float* __restrict__ mIn,
               float* __restrict__ outh, float* __restrict__ outm)
{
    __shared__ unsigned short smem[57344];   // 112 KB

    const int nwg = gridDim.x;
    const int wg  = (blockIdx.x & 7) * (nwg >> 3) + (blockIdx.x >> 3);
    const int m0  = (wg >> 2) * 256;
    const int c0  = (wg & 3) * 64;

    const int tid  = threadIdx.x;
    const int lane = tid & 63;
    const int w    = tid >> 6;
    const int fr   = lane & 15;
    const int g    = lane >> 4;
    const int wm   = (w >> 2) * 128;
    const int wn   = (w & 3) * 48;

    const int srow   = tid >> 3;
    const int schunk = ((tid & 7) ^ (srow & 7)) * 8;
    const int sdst   = w * 512;

    v4f acc[8][3];
#pragma unroll
    for (int i = 0; i < 8; ++i)
#pragma unroll
        for (int j = 0; j < 3; ++j) acc[i][j] = v4f{0.f, 0.f, 0.f, 0.f};

    const int nt = K >> 6;

#define STAGE_A(t, bi, i)                                                      \
    { const int k0 = (t) * 64;                                                 \
      const unsigned short* Ab; int Al; int Ao;                                \
      if (k0 < kswitch) { Ab = A;  Al = lda;  Ao = k0; }                       \
      else              { Ab = A2; Al = lda2; Ao = k0 - kswitch; }             \
      glds16(Ab + (long)(m0 + (i) * 64 + srow) * Al + Ao + schunk,             \
             &smem[(bi) * 16384 + (i) * 4096 + sdst]); }
#define STAGE_B(t, bi, i)                                                      \
    { const int k0 = (t) * 64;                                                 \
      glds16(Bt + (long)((i) * 256 + c0 + srow) * ldb + k0 + schunk,           \
             &smem[32768 + (bi) * 12288 + (i) * 4096 + sdst]); }

#pragma unroll
    for (int i = 0; i < 4; ++i) STAGE_A(0, 0, i);
#pragma unroll
    for (int i = 0; i < 3; ++i) STAGE_B(0, 0, i);

    for (int t = 0; t < nt; ++t) {
        __syncthreads();   // implicit vmcnt(0): tile t landed; prior reads done

        const unsigned short* Ar = smem + (t & 1) * 16384;
        const unsigned short* Br = smem + 32768 + (t & 1) * 12288;
        const int nb = (t + 1) & 1;
        const bool more = (t + 1 < nt);

#pragma unroll
        for (int ks = 0; ks < 2; ++ks) {
            v8bf bf[3];
#pragma unroll
            for (int ni = 0; ni < 3; ++ni) {
                const int r = wn + ni * 16 + fr;
                bf[ni] = *reinterpret_cast<const v8bf*>(
                    &Br[r * 64 + ((ks * 4 + g) ^ (r & 7)) * 8]);
            }
#pragma unroll
            for (int hh = 0; hh < 2; ++hh) {
                v8bf af[4];
#pragma unroll
                for (int mi = 0; mi < 4; ++mi) {
                    const int r = wm + (hh * 4 + mi) * 16 + fr;
                    af[mi] = *reinterpret_cast<const v8bf*>(
                        &Ar[r * 64 + ((ks * 4 + g) ^ (r & 7)) * 8]);
                }
                if (more) {
                    const int ph = ks * 2 + hh;
                    if (ph == 0)      { STAGE_A(t + 1, nb, 0); STAGE_A(t + 1, nb, 1); }
                    else if (ph == 1) { STAGE_A(t + 1, nb, 2); STAGE_A(t + 1, nb, 3); }
                    else if (ph == 2) { STAGE_B(t + 1, nb, 0); STAGE_B(t + 1, nb, 1); }
                    else              { STAGE_B(t + 1, nb, 2); }
                }
                __builtin_amdgcn_s_setprio(1);
#pragma unroll
                for (int mi = 0; mi < 4; ++mi)
#pragma unroll
                    for (int ni = 0; ni < 3; ++ni)
                        acc[hh * 4 + mi][ni] = __builtin_amdgcn_mfma_f32_16x16x32_bf16(
                            af[mi], bf[ni], acc[hh * 4 + mi][ni], 0, 0, 0);
                __builtin_amdgcn_s_setprio(0);
            }
        }
    }
#undef STAGE_A
#undef STAGE_B

    __syncthreads();

    unsigned short* Lt = smem;               // [256][194] bf16
#pragma unroll
    for (int mi = 0; mi < 8; ++mi) {
#pragma unroll
        for (int ni = 0; ni < 3; ++ni) {
            const int j  = wn + ni * 16 + fr;
            const int cg = ((j >> 6) << 8) + c0 + (j & 63);
            const float bn = bias[cg];
            const int rl = wm + mi * 16 + g * 4;
#pragma unroll
            for (int r = 0; r < 4; ++r)
                Lt[(rl + r) * 194 + j] = f2u(acc[mi][ni][r] + bn);
        }
    }
    __syncthreads();

    const int b     = m0 >> 10;
    const int pbase = m0 & 1023;
    const int pl    = tid & 255;
    const int ch    = tid >> 8;
#pragma unroll 4
    for (int cc = 0; cc < 32; ++cc) {
        const int cl = ch * 32 + cc;
        const float mo  = u2f(Lt[pl * 194 + cl]);
        const float mg  = u2f(Lt[pl * 194 + 64 + cl]);
        const float mi_ = u2f(Lt[pl * 194 + 128 + cl]);
        const long gi = ((long)(b * 256 + c0 + cl)) * 1024 + pbase + pl;
        const float mv = mIn[gi];
        const float ms = sigmoidf_(mi_);
        const float nm = (1.f - ms) * mv + ms * tanhf_(mg);
        const float nh = sigmoidf_(mo) * nm;
        outh[gi] = nh;
        outm[gi] = nm;
    }
}

// ---------------------------------------------------------------------------
// Fused attention v8c: as v8b but the P/V slot swizzle uses (row>>2)&3.
// R21 analysis: with (row>>1)&3, the wave's 4 g-subgroups (rows stride 4)
// map to masks {0,2,0,2}^base -> pairs collide -> 4-way P-WRITE conflicts
// (the remaining 6.29M). (row>>2)&3 makes (g*4)>>2 = g -> all distinct;
// read-side quarter-waves still 2-way (4 rows per slot value, split even/odd
// bank halves).
// ---------------------------------------------------------------------------
__global__ __launch_bounds__(512, 4)
void attn_fused(const unsigned short* __restrict__ Qb, long sQ, int ldq,
                const unsigned short* __restrict__ K0, long sK0, int ldk0,
                const unsigned short* __restrict__ V0,
                const unsigned short* __restrict__ K1, long sK1, int ldk1,
                const unsigned short* __restrict__ V1,
                unsigned short* __restrict__ Out, long sO)
{
    __shared__ unsigned short Qs[128 * 128];  // 32 KB
    __shared__ unsigned short Ks[32 * 128];   //  8 KB
    __shared__ unsigned short Vs[256 * 32];   // 16 KB
    __shared__ unsigned short Ps[128 * 32];   //  8 KB

    const int id = blockIdx.x;            // 0..511
    const int c8 = id & 7;
    const int k  = id >> 3;               // 0..63
    const int z  = c8 * 8 + (k >> 3);     // (branch,batch)
    const int p0 = (k & 7) * 128;

    const int b  = (z < 32) ? z : z - 32;
    const unsigned short* Kp; const unsigned short* Vp; int ldk, outoff;
    if (z < 32) { Kp = K0 + (long)b * sK0; Vp = V0 + (long)b * 262144L; ldk = ldk0; outoff = 0; }
    else        { Kp = K1 + (long)b * sK1; Vp = V1 + (long)b * 262144L; ldk = ldk1; outoff = 256; }
    const unsigned short* Qp = Qb + (long)b * sQ;
    Out += (long)b * sO;

    const int tid  = threadIdx.x;
    const int lane = tid & 63;
    const int w    = tid >> 6;
    const int fr   = lane & 15;
    const int g    = lane >> 4;
    const int wp   = w >> 2;              // p-half (64 rows)
    const int wq   = w & 3;
    const int srow0 = wp * 64 + (wq >> 1) * 32;   // S: 32 rows per wave
    const int kc0   = (wq & 1) * 16;              // S: kv-col half
    const int kr    = kc0 + fr;                   // K row (0..31)
    const int wc    = wq * 64;                    // PV: c-quarter

    v4f vacc[4][4];
#pragma unroll
    for (int i = 0; i < 4; ++i)
#pragma unroll
        for (int j = 0; j < 4; ++j) vacc[i][j] = v4f{0.f, 0.f, 0.f, 0.f};
    float rp[2][4];
#pragma unroll
    for (int i = 0; i < 2; ++i)
#pragma unroll
        for (int r = 0; r < 4; ++r) rp[i][r] = 0.f;

    const int qkrow  = tid >> 4;                          // 0..31
    const int qkchk  = ((tid & 15) ^ (qkrow & 7)) * 8;
    const int vrow   = tid >> 2;                          // 0..127
    const int vchk   = ((tid & 3) ^ ((vrow >> 2) & 3)) * 8;
    const int sdst   = w * 512;

#define STAGE_Q()                                                              \
    { _Pragma("unroll")                                                        \
      for (int i = 0; i < 4; ++i)                                              \
          glds16(Qp + (long)(p0 + i * 32 + qkrow) * ldq + qkchk,               \
                 &Qs[i * 4096 + sdst]); }
#define STAGE_K(t)                                                             \
    glds16(Kp + (long)((t) * 32 + qkrow) * ldk + qkchk, &Ks[sdst]);
#define STAGE_V(t)                                                             \
    { const int kv0 = (t) * 32;                                                \
      _Pragma("unroll")                                                        \
      for (int i = 0; i < 2; ++i)                                              \
          glds16(Vp + (long)(i * 128 + vrow) * 1024 + kv0 + vchk,              \
                 &Vs[i * 4096 + sdst]); }

    STAGE_Q();
    STAGE_K(0);

    for (int t = 0; t < 32; ++t) {
        __syncthreads();              // drains Q(+K0)/K(t); PV(t-1) LDS reads done
        STAGE_V(t);                   // drained at barrier-2, covered by S+exp

        // ---- S = Q @ K^T (per wave: 32p x 16kv, K=128), exp, write P
        v4f sacc[2];
#pragma unroll
        for (int mi = 0; mi < 2; ++mi) sacc[mi] = v4f{0.f, 0.f, 0.f, 0.f};
        __builtin_amdgcn_s_setprio(1);
#pragma unroll
        for (int ks = 0; ks < 4; ++ks) {
            const v8bf kf = *reinterpret_cast<const v8bf*>(
                &Ks[kr * 128 + ((ks * 4 + g) ^ (kr & 7)) * 8]);
#pragma unroll
            for (int mi = 0; mi < 2; ++mi) {
                const int qrow = srow0 + mi * 16 + fr;
                const v8bf qf = *reinterpret_cast<const v8bf*>(
                    &Qs[qrow * 128 + ((ks * 4 + g) ^ (qrow & 7)) * 8]);
                sacc[mi] = __builtin_amdgcn_mfma_f32_16x16x32_bf16(qf, kf, sacc[mi], 0, 0, 0);
            }
        }
        __builtin_amdgcn_s_setprio(0);
#pragma unroll
        for (int mi = 0; mi < 2; ++mi)
#pragma unroll
            for (int r = 0; r < 4; ++r) {
                const float e = __expf(sacc[mi][r]);
                rp[mi][r] += e;
                const int prow = srow0 + mi * 16 + g * 4 + r;
                Ps[prow * 32 + (((kr >> 3) ^ ((prow >> 2) & 3)) << 3) + (kr & 7)] = f2u(e);
            }

        __syncthreads();              // drains V(t); Ps visible; Ks reads done
        if (t < 31) STAGE_K(t + 1);   // drained at barrier-1(t+1), covered by PV

        // ---- PV: vacc += P @ V^T (per wave: 64p x 64c, K=32 -> 1 MFMA each)
        __builtin_amdgcn_s_setprio(1);
        {
            v8bf pf[4], vf[4];
#pragma unroll
            for (int mi = 0; mi < 4; ++mi) {
                const int pr = wp * 64 + mi * 16 + fr;
                pf[mi] = *reinterpret_cast<const v8bf*>(
                    &Ps[pr * 32 + ((g ^ ((pr >> 2) & 3)) << 3)]);
            }
#pragma unroll
            for (int ni = 0; ni < 4; ++ni) {
                const int vr = wc + ni * 16 + fr;
                vf[ni] = *reinterpret_cast<const v8bf*>(
                    &Vs[vr * 32 + ((g ^ ((vr >> 2) & 3)) << 3)]);
            }
#pragma unroll
            for (int mi = 0; mi < 4; ++mi)
#pragma unroll
                for (int ni = 0; ni < 4; ++ni)
                    vacc[mi][ni] = __builtin_amdgcn_mfma_f32_16x16x32_bf16(pf[mi], vf[ni], vacc[mi][ni], 0, 0, 0);
        }
        __builtin_amdgcn_s_setprio(0);
    }
#undef STAGE_Q
#undef STAGE_K
#undef STAGE_V

    __syncthreads();
    float* red = reinterpret_cast<float*>(Ps);
#pragma unroll
    for (int mi = 0; mi < 2; ++mi)
#pragma unroll
        for (int r = 0; r < 4; ++r) {
            float v = rp[mi][r];
            v += __shfl_xor(v, 1);
            v += __shfl_xor(v, 2);
            v += __shfl_xor(v, 4);
            v += __shfl_xor(v, 8);
            if (fr == 0) red[(wq & 1) * 128 + srow0 + mi * 16 + g * 4 + r] = v;
        }
    __syncthreads();

#pragma unroll
    for (int mi = 0; mi < 4; ++mi)
#pragma unroll
        for (int r = 0; r < 4; ++r) {
            const int pl = wp * 64 + mi * 16 + g * 4 + r;
            const float inv = 1.f / (red[pl] + red[128 + pl]);
#pragma unroll
            for (int ni = 0; ni < 4; ++ni)
                Out[(long)(p0 + pl) * 512 + outoff + wc + ni * 16 + fr]
                    = f2u(vacc[mi][ni][r] * inv);
        }
}

// ---------------------------------------------------------------------------
extern "C" void kernel_launch(void* const* d_in, const int* in_sizes, int n_in,
                              void* d_out, int out_size, void* d_ws, size_t ws_size,
                              hipStream_t stream)
{
    const float* h   = (const float*)d_in[0];
    const float* m   = (const float*)d_in[1];
    const float* Wq  = (const float*)d_in[2];
    const float* bq  = (const float*)d_in[3];
    const float* Wk  = (const float*)d_in[4];
    const float* bk  = (const float*)d_in[5];
    const float* Wv  = (const float*)d_in[6];
    const float* bv  = (const float*)d_in[7];
    const float* Wk2 = (const float*)d_in[8];
    const float* bk2 = (const float*)d_in[9];
    const float* Wv2 = (const float*)d_in[10];
    const float* bv2 = (const float*)d_in[11];
    const float* Wz  = (const float*)d_in[12];
    const float* bz  = (const float*)d_in[13];
    const float* Wm  = (const float*)d_in[14];
    const float* bm  = (const float*)d_in[15];

    char* ws = (char*)d_ws;
    if (ws_size < (size_t)WS_TOTAL) return;

    unsigned short* hT  = (unsigned short*)(ws + OFF_HBT);
    unsigned short* qkh = (unsigned short*)(ws + OFF_QKH);
    unsigned short* qkm = (unsigned short*)(ws + OFF_QKM);
    unsigned short* vh  = (unsigned short*)(ws + OFF_VH);
    unsigned short* vm  = (unsigned short*)(ws + OFF_VM);
    unsigned short* zct = (unsigned short*)(ws + OFF_ZCT);
    unsigned short* wA  = (unsigned short*)(ws + OFF_W);
    float*          bA  = (float*)(ws + OFF_B);

    float* outh = (float*)d_out;
    float* outm = outh + 8388608L;

    // pack + bias-fold + transpose in ONE dispatch
    prep<<<dim3(10124), dim3(256), 0, stream>>>(
        h, m, Wq, Wk, Wv, Wk2, Wv2, Wz, Wm,
        bq, bk, bk2, bv, bv2, bz, bm, ws);

    // 5 GEMM jobs (projections, v's, Wf fold) in ONE dispatch, XCD-swizzled
    gemm_multi<<<dim3(1816), dim3(256), 0, stream>>>(ws);

    // fused attention, both branches, XCD-swizzled 1D grid (128-p tiles, KVBLK=32)
    attn_fused<<<dim3(512), dim3(512), 0, stream>>>(
        qkh, 262144L, 256,
        qkh + 128, 262144L, 256, vh,
        qkm, 131072L, 128, vm,
        zct, 524288L);

    // comb (= [zcatT | h^T] @ Wf^T + bfused) with FUSED gating epilogue
    comb_gemm<<<dim3(512), dim3(512), 0, stream>>>(
        zct, 512, hT, 256, 512,
        wA + W_F, 768, 768, bA + B_F, m, outh, outm);
}

// Round 23
// 197.599 us; speedup vs baseline: 1.0174x; 1.0174x over previous
//
#include <hip/hip_runtime.h>
#include <hip/hip_bf16.h>

typedef __bf16  v8bf __attribute__((ext_vector_type(8)));
typedef float   v4f  __attribute__((ext_vector_type(4)));
typedef float   f4   __attribute__((ext_vector_type(4)));
typedef unsigned short us8 __attribute__((ext_vector_type(8)));
typedef unsigned short us4 __attribute__((ext_vector_type(4)));
typedef unsigned int u32;

#define BATCH 32
#define CDIM  256
#define HW    1024

// ---- shared ws offsets (bytes) -------------------------------------------
#define OFF_HBT 0L
#define OFF_MBT (OFF_HBT + 16777216L)   // m_bfT
#define OFF_QKH (OFF_MBT + 16777216L)   // qk_h  [32][1024][256]
#define OFF_QKM (OFF_QKH + 16777216L)   // k2_m  [32][1024][128]
#define OFF_VH  (OFF_QKM + 8388608L)    // v_h   [32][256][1024]
#define OFF_VM  (OFF_VH  + 16777216L)   // v_m
#define OFF_ZCT (OFF_VM  + 16777216L)   // zcatT [32][1024][512]
#define OFF_W   (OFF_ZCT + 33554432L)   // weights (1933312 shorts)
#define OFF_B   (OFF_W   + 3866624L)    // biases (2944 floats)
#define WS_TOTAL (OFF_B + 2944L * 4)
// weight sub-offsets (shorts from OFF_W)
#define W_QK  0
#define W_K2  65536
#define W_V   98304
#define W_V2  163840
#define W_M   491520
#define W_ZT  1081344
#define W_F   1343488
// bias sub-offsets (floats from OFF_B)
#define B_QK  0
#define B_K2  256
#define B_V   384
#define B_V2  640
#define B_F   2176

__device__ inline unsigned short f2u(float x) {
    __hip_bfloat16 h = __float2bfloat16(x);
    union { __hip_bfloat16 h; unsigned short u; } cv; cv.h = h; return cv.u;
}
__device__ inline float u2f(unsigned short u) {
    union { unsigned short u; __hip_bfloat16 h; } cv; cv.u = u; return __bfloat162float(cv.h);
}
__device__ inline float sigmoidf_(float x) {
    x = fminf(fmaxf(x, -30.f), 30.f);
    return 1.f / (1.f + __expf(-x));
}
__device__ inline float tanhf_(float x) {
    x = fminf(fmaxf(x, -15.f), 15.f);
    float e = __expf(2.f * x);
    return (e - 1.f) / (e + 1.f);
}
// direct global->LDS DMA, 16B per lane; lds dest is wave-uniform base + lane*16
__device__ inline void glds16(const unsigned short* g, unsigned short* l) {
    __builtin_amdgcn_global_load_lds(
        (const __attribute__((address_space(1))) u32*)g,
        (__attribute__((address_space(3))) u32*)l, 16, 0, 0);
}

// ---------------------------------------------------------------------------
// prep: weight pack (blocks 0..6024) + bias fold (6025..6027) +
//       transposing fp32->bf16 convert of h,m (6028..10123).
// ---------------------------------------------------------------------------
__global__ __launch_bounds__(256)
void prep(const float* __restrict__ hsrc, const float* __restrict__ msrc,
          const float* __restrict__ Wq, const float* __restrict__ Wk,
          const float* __restrict__ Wv, const float* __restrict__ Wk2,
          const float* __restrict__ Wv2, const float* __restrict__ Wz,
          const float* __restrict__ Wm,
          const float* __restrict__ bq, const float* __restrict__ bk,
          const float* __restrict__ bk2, const float* __restrict__ bv,
          const float* __restrict__ bv2, const float* __restrict__ bz,
          const float* __restrict__ bm,
          char* __restrict__ ws)
{
    __shared__ float t[64][68];
    unsigned short* wdst = (unsigned short*)(ws + OFF_W);
    float*          bdst = (float*)(ws + OFF_B);
    const int bid = blockIdx.x;
    const int tid = threadIdx.x;

    if (bid < 6025) {                       // ---- weight pack
        const int gid = bid * 256 + tid;
        if (gid < 1081344) {
            const float* s; int off;
            if      (gid <   32768) { s = Wq;  off = gid; }
            else if (gid <   65536) { s = Wk;  off = gid -   32768; }
            else if (gid <   98304) { s = Wk2; off = gid -   65536; }
            else if (gid <  163840) { s = Wv;  off = gid -   98304; }
            else if (gid <  229376) { s = Wv2; off = gid -  163840; }
            else if (gid <  491520) { s = Wz;  off = gid -  229376; }
            else                    { s = Wm;  off = gid -  491520; }
            wdst[gid] = f2u(s[off]);
        } else if (gid < 1343488) {
            const int idx = gid - 1081344;          // WzT[k][j] = Wz[j][k]
            const int k = idx >> 9, j = idx & 511;
            wdst[gid] = f2u(Wz[j * 512 + k]);
        } else if (gid < 1540096) {
            const int idx = gid - 1343488;          // Wf[o][512+r] = Wm[o][512+r]
            const int o = idx >> 8, kk = 512 + (idx & 255);
            wdst[W_F + o * 768 + kk] = f2u(Wm[o * 768 + kk]);
        } else {
            const int bi = gid - 1540096;
            if (bi < 2176) {
                const float* s; int off;
                if      (bi <  128) { s = bq;  off = bi; }
                else if (bi <  256) { s = bk;  off = bi -  128; }
                else if (bi <  384) { s = bk2; off = bi -  256; }
                else if (bi <  640) { s = bv;  off = bi -  384; }
                else if (bi <  896) { s = bv2; off = bi -  640; }
                else if (bi < 1408) { s = bz;  off = bi -  896; }
                else                { s = bm;  off = bi - 1408; }
                bdst[bi] = s[off];
            }
        }
    } else if (bid < 6028) {                // ---- bfused = bm + Wm[:, :512] @ bz
        const int o = (bid - 6025) * 256 + tid;
        if (o < 768) {
            float s = bm[o];
            const float* r = Wm + (long)o * 768;
#pragma unroll 8
            for (int j = 0; j < 512; ++j) s += r[j] * bz[j];
            bdst[B_F + o] = s;
        }
    } else {                                // ---- transpose_cvt
        const int tz = bid - 6028;          // 0..4095
        const int z  = tz >> 6;             // 0..63
        const int p0 = (tz & 15) * 64;
        const int c0 = ((tz >> 4) & 3) * 64;
        const float* src = (z < BATCH) ? hsrc + (long)z * CDIM * HW
                                       : msrc + (long)(z - BATCH) * CDIM * HW;
        unsigned short* dst = (unsigned short*)(ws + ((z < BATCH) ? OFF_HBT : OFF_MBT))
                              + (long)((z < BATCH) ? z : z - BATCH) * HW * CDIM;
        const int r  = tid >> 4;
        const int c4 = (tid & 15) * 4;
#pragma unroll
        for (int i = 0; i < 4; ++i) {
            const f4 v = *reinterpret_cast<const f4*>(src + (long)(c0 + r + 16 * i) * HW + p0 + c4);
            t[r + 16 * i][c4 + 0] = v[0];
            t[r + 16 * i][c4 + 1] = v[1];
            t[r + 16 * i][c4 + 2] = v[2];
            t[r + 16 * i][c4 + 3] = v[3];
        }
        __syncthreads();
#pragma unroll
        for (int i = 0; i < 4; ++i) {
            const int pr = r + 16 * i;
            us4 o;
#pragma unroll
            for (int j = 0; j < 4; ++j) o[j] = f2u(t[c4 + j][pr]);
            *reinterpret_cast<us4*>(dst + (long)(p0 + pr) * CDIM + c0 + c4) = o;
        }
    }
}

// ---------------------------------------------------------------------------
// Shared GEMM core v3 (R20): 128x128 tile, BK=64, st-swizzled LDS, A/B
// double-buffered, ONE barrier per K-tile, staging interleaved into compute.
// smem = 32768 shorts (64KB); Cs bounce overlays smem in the epilogue.
// ---------------------------------------------------------------------------
__device__ __forceinline__
void gemm_core(const unsigned short* __restrict__ A, int lda,
               const unsigned short* __restrict__ A2, int lda2, int kswitch,
               const unsigned short* __restrict__ Bt, int ldb,
               unsigned short* __restrict__ Cp, int ldc,
               int K, const float* __restrict__ bias, int biasMode,
               int m0, int n0,
               unsigned short* smem)
{
    const int tid  = threadIdx.x;
    const int lane = tid & 63;
    const int w    = tid >> 6;

    v4f acc[4][4];
#pragma unroll
    for (int i = 0; i < 4; ++i)
#pragma unroll
        for (int j = 0; j < 4; ++j) acc[i][j] = v4f{0.f, 0.f, 0.f, 0.f};

    const int wm   = (w >> 1) * 64;
    const int wn   = (w & 1) * 64;
    const int fr   = lane & 15;
    const int g    = lane >> 4;

    const int arow = (w << 3) + (lane >> 3);
    const int acol = (((lane & 7) ^ ((lane >> 3) & 7)) * 8);
    const int lbase = (w << 9);

    const int nt = K >> 6;

#define GSTAGE_A(t, bi, i)                                                     \
    { const int k0 = (t) * 64;                                                 \
      const unsigned short* Ab; int Al; int Ao;                                \
      if (k0 < kswitch) { Ab = A;  Al = lda;  Ao = k0; }                       \
      else              { Ab = A2; Al = lda2; Ao = k0 - kswitch; }             \
      glds16(Ab + (long)(m0 + (i) * 32 + arow) * Al + Ao + acol,               \
             &smem[(bi) * 8192 + (i) * 2048 + lbase]); }
#define GSTAGE_B(t, bi, i)                                                     \
    { const int k0 = (t) * 64;                                                 \
      glds16(Bt + (long)(n0 + (i) * 32 + arow) * ldb + k0 + acol,              \
             &smem[16384 + (bi) * 8192 + (i) * 2048 + lbase]); }

    // prologue: stage tile 0 -> buf 0
#pragma unroll
    for (int i = 0; i < 4; ++i) { GSTAGE_A(0, 0, i); GSTAGE_B(0, 0, i); }

    for (int t = 0; t < nt; ++t) {
        __syncthreads();   // implicit vmcnt(0): tile t landed; reads of buf[(t+1)&1] done

        const unsigned short* Ar = smem + (t & 1) * 8192;
        const unsigned short* Br = smem + 16384 + (t & 1) * 8192;
        const int nb = (t + 1) & 1;
        const bool more = (t + 1 < nt);

#pragma unroll
        for (int ks = 0; ks < 2; ++ks) {
            const int slot = ((ks * 4 + g) ^ (fr & 7)) * 8;
            v8bf af[4], bfv[4];
#pragma unroll
            for (int mi = 0; mi < 4; ++mi)
                af[mi] = *reinterpret_cast<const v8bf*>(&Ar[(wm + mi * 16 + fr) * 64 + slot]);
#pragma unroll
            for (int ni = 0; ni < 4; ++ni)
                bfv[ni] = *reinterpret_cast<const v8bf*>(&Br[(wn + ni * 16 + fr) * 64 + slot]);
            // interleave next-tile staging with this phase's MFMAs
            if (more) {
                if (ks == 0) { GSTAGE_A(t + 1, nb, 0); GSTAGE_A(t + 1, nb, 1);
                               GSTAGE_A(t + 1, nb, 2); GSTAGE_A(t + 1, nb, 3); }
                else         { GSTAGE_B(t + 1, nb, 0); GSTAGE_B(t + 1, nb, 1);
                               GSTAGE_B(t + 1, nb, 2); GSTAGE_B(t + 1, nb, 3); }
            }
            __builtin_amdgcn_s_setprio(1);
#pragma unroll
            for (int mi = 0; mi < 4; ++mi)
#pragma unroll
                for (int ni = 0; ni < 4; ++ni)
                    acc[mi][ni] = __builtin_amdgcn_mfma_f32_16x16x32_bf16(af[mi], bfv[ni], acc[mi][ni], 0, 0, 0);
            __builtin_amdgcn_s_setprio(0);
        }
    }
#undef GSTAGE_A
#undef GSTAGE_B

    __syncthreads();   // last tile's LDS reads done; smem reusable as Cs

    // ---- epilogue: acc+bias -> Cs[128][132] bf16, then coalesced us8 stores
    unsigned short* Cs = smem;
#pragma unroll
    for (int mi = 0; mi < 4; ++mi) {
#pragma unroll
        for (int ni = 0; ni < 4; ++ni) {
            const int col = wn + ni * 16 + fr;
            const int rb  = wm + mi * 16 + g * 4;
            const float bn = (biasMode == 1) ? bias[n0 + col] : 0.f;
#pragma unroll
            for (int r = 0; r < 4; ++r) {
                float x = acc[mi][ni][r] + bn;
                if (biasMode == 2) x += bias[m0 + rb + r];
                Cs[(rb + r) * 132 + col] = f2u(x);
            }
        }
    }
    __syncthreads();

    const int orow = tid >> 4;          // 0..15
    const int och  = (tid & 15) * 8;    // 0..120
#pragma unroll
    for (int i = 0; i < 8; ++i) {
        const int row = i * 16 + orow;
        *reinterpret_cast<us8*>(Cp + (long)(m0 + row) * ldc + n0 + och) =
            *reinterpret_cast<const us8*>(&Cs[row * 132 + och]);
    }
}

// 5 GEMM jobs in one dispatch (1816 blocks), XCD-locality swizzled (R21:
// consecutive job ids per XCD -> same-batch panels L2-resident; fixed the
// L3-bound staging that pinned 3 different schedules at ~76us).
__global__ __launch_bounds__(256)
void gemm_multi(char* __restrict__ ws)
{
    __shared__ unsigned short smem[32768];   // 64 KB: A/B dbuf + Cs bounce
    unsigned short* wA = (unsigned short*)(ws + OFF_W);
    float*          bA = (float*)(ws + OFF_B);
    const int raw = blockIdx.x;
    const int id  = (raw & 7) * 227 + (raw >> 3);   // bijective: 1816 = 8*227

    if (id < 512) {
        const int b = id >> 4, x = id & 7, y = (id >> 3) & 1;
        const unsigned short* A = (unsigned short*)(ws + OFF_HBT) + (long)b * 262144;
        gemm_core(A, 256, A, 256, 1 << 30, wA + W_QK, 256,
                  (unsigned short*)(ws + OFF_QKH) + (long)b * 262144, 256,
                  256, bA + B_QK, 1, x * 128, y * 128, smem);
    } else if (id < 768) {
        const int idx = id - 512, b = idx >> 3, x = idx & 7;
        const unsigned short* A = (unsigned short*)(ws + OFF_MBT) + (long)b * 262144;
        gemm_core(A, 256, A, 256, 1 << 30, wA + W_K2, 256,
                  (unsigned short*)(ws + OFF_QKM) + (long)b * 131072, 128,
                  256, bA + B_K2, 1, x * 128, 0, smem);
    } else if (id < 1280) {
        const int idx = id - 768, b = idx >> 4, x = idx & 1, y = (idx >> 1) & 7;
        gemm_core(wA + W_V, 256, wA + W_V, 256, 1 << 30,
                  (unsigned short*)(ws + OFF_HBT) + (long)b * 262144, 256,
                  (unsigned short*)(ws + OFF_VH) + (long)b * 262144, 1024,
                  256, bA + B_V, 2, x * 128, y * 128, smem);
    } else if (id < 1792) {
        const int idx = id - 1280, b = idx >> 4, x = idx & 1, y = (idx >> 1) & 7;
        gemm_core(wA + W_V2, 256, wA + W_V2, 256, 1 << 30,
                  (unsigned short*)(ws + OFF_MBT) + (long)b * 262144, 256,
                  (unsigned short*)(ws + OFF_VM) + (long)b * 262144, 1024,
                  256, bA + B_V2, 2, x * 128, y * 128, smem);
    } else {
        const int idx = id - 1792, x = idx % 6, y = idx / 6;
        gemm_core(wA + W_M, 768, wA + W_M, 768, 1 << 30, wA + W_ZT, 512,
                  wA + W_F, 768, 512, bA, 0, x * 128, y * 128, smem);
    }
}

// ---------------------------------------------------------------------------
// comb_gemm v4 + FUSED GATING (R16, passed): 256-row x 3x64-col gather, one
// barrier per K-tile, staging interleaved into compute phases.
// ---------------------------------------------------------------------------
__global__ __launch_bounds__(512, 2)
void comb_gemm(const unsigned short* __restrict__ A, int lda,
               const unsigned short* __restrict__ A2, int lda2, int kswitch,
               const unsigned short* __restrict__ Bt, int ldb,
               int K, const float* __restrict__ bias,
               const float* __restrict__ mIn,
               float* __restrict__ outh, float* __restrict__ outm)
{
    __shared__ unsigned short smem[57344];   // 112 KB

    const int nwg = gridDim.x;
    const int wg  = (blockIdx.x & 7) * (nwg >> 3) + (blockIdx.x >> 3);
    const int m0  = (wg >> 2) * 256;
    const int c0  = (wg & 3) * 64;

    const int tid  = threadIdx.x;
    const int lane = tid & 63;
    const int w    = tid >> 6;
    const int fr   = lane & 15;
    const int g    = lane >> 4;
    const int wm   = (w >> 2) * 128;
    const int wn   = (w & 3) * 48;

    const int srow   = tid >> 3;
    const int schunk = ((tid & 7) ^ (srow & 7)) * 8;
    const int sdst   = w * 512;

    v4f acc[8][3];
#pragma unroll
    for (int i = 0; i < 8; ++i)
#pragma unroll
        for (int j = 0; j < 3; ++j) acc[i][j] = v4f{0.f, 0.f, 0.f, 0.f};

    const int nt = K >> 6;

#define STAGE_A(t, bi, i)                                                      \
    { const int k0 = (t) * 64;                                                 \
      const unsigned short* Ab; int Al; int Ao;                                \
      if (k0 < kswitch) { Ab = A;  Al = lda;  Ao = k0; }                       \
      else              { Ab = A2; Al = lda2; Ao = k0 - kswitch; }             \
      glds16(Ab + (long)(m0 + (i) * 64 + srow) * Al + Ao + schunk,             \
             &smem[(bi) * 16384 + (i) * 4096 + sdst]); }
#define STAGE_B(t, bi, i)                                                      \
    { const int k0 = (t) * 64;                                                 \
      glds16(Bt + (long)((i) * 256 + c0 + srow) * ldb + k0 + schunk,           \
             &smem[32768 + (bi) * 12288 + (i) * 4096 + sdst]); }

#pragma unroll
    for (int i = 0; i < 4; ++i) STAGE_A(0, 0, i);
#pragma unroll
    for (int i = 0; i < 3; ++i) STAGE_B(0, 0, i);

    for (int t = 0; t < nt; ++t) {
        __syncthreads();   // implicit vmcnt(0): tile t landed; prior reads done

        const unsigned short* Ar = smem + (t & 1) * 16384;
        const unsigned short* Br = smem + 32768 + (t & 1) * 12288;
        const int nb = (t + 1) & 1;
        const bool more = (t + 1 < nt);

#pragma unroll
        for (int ks = 0; ks < 2; ++ks) {
            v8bf bf[3];
#pragma unroll
            for (int ni = 0; ni < 3; ++ni) {
                const int r = wn + ni * 16 + fr;
                bf[ni] = *reinterpret_cast<const v8bf*>(
                    &Br[r * 64 + ((ks * 4 + g) ^ (r & 7)) * 8]);
            }
#pragma unroll
            for (int hh = 0; hh < 2; ++hh) {
                v8bf af[4];
#pragma unroll
                for (int mi = 0; mi < 4; ++mi) {
                    const int r = wm + (hh * 4 + mi) * 16 + fr;
                    af[mi] = *reinterpret_cast<const v8bf*>(
                        &Ar[r * 64 + ((ks * 4 + g) ^ (r & 7)) * 8]);
                }
                if (more) {
                    const int ph = ks * 2 + hh;
                    if (ph == 0)      { STAGE_A(t + 1, nb, 0); STAGE_A(t + 1, nb, 1); }
                    else if (ph == 1) { STAGE_A(t + 1, nb, 2); STAGE_A(t + 1, nb, 3); }
                    else if (ph == 2) { STAGE_B(t + 1, nb, 0); STAGE_B(t + 1, nb, 1); }
                    else              { STAGE_B(t + 1, nb, 2); }
                }
                __builtin_amdgcn_s_setprio(1);
#pragma unroll
                for (int mi = 0; mi < 4; ++mi)
#pragma unroll
                    for (int ni = 0; ni < 3; ++ni)
                        acc[hh * 4 + mi][ni] = __builtin_amdgcn_mfma_f32_16x16x32_bf16(
                            af[mi], bf[ni], acc[hh * 4 + mi][ni], 0, 0, 0);
                __builtin_amdgcn_s_setprio(0);
            }
        }
    }
#undef STAGE_A
#undef STAGE_B

    __syncthreads();

    unsigned short* Lt = smem;               // [256][194] bf16
#pragma unroll
    for (int mi = 0; mi < 8; ++mi) {
#pragma unroll
        for (int ni = 0; ni < 3; ++ni) {
            const int j  = wn + ni * 16 + fr;
            const int cg = ((j >> 6) << 8) + c0 + (j & 63);
            const float bn = bias[cg];
            const int rl = wm + mi * 16 + g * 4;
#pragma unroll
            for (int r = 0; r < 4; ++r)
                Lt[(rl + r) * 194 + j] = f2u(acc[mi][ni][r] + bn);
        }
    }
    __syncthreads();

    const int b     = m0 >> 10;
    const int pbase = m0 & 1023;
    const int pl    = tid & 255;
    const int ch    = tid >> 8;
#pragma unroll 4
    for (int cc = 0; cc < 32; ++cc) {
        const int cl = ch * 32 + cc;
        const float mo  = u2f(Lt[pl * 194 + cl]);
        const float mg  = u2f(Lt[pl * 194 + 64 + cl]);
        const float mi_ = u2f(Lt[pl * 194 + 128 + cl]);
        const long gi = ((long)(b * 256 + c0 + cl)) * 1024 + pbase + pl;
        const float mv = mIn[gi];
        const float ms = sigmoidf_(mi_);
        const float nm = (1.f - ms) * mv + ms * tanhf_(mg);
        const float nh = sigmoidf_(mo) * nm;
        outh[gi] = nh;
        outm[gi] = nm;
    }
}

// ---------------------------------------------------------------------------
// Fused attention v8b (R18/R21, best measured: 72.1us, 6.29M conflicts):
// 128-p tiles, KVBLK=32, LDS 64KB, 2 blocks/CU, (row>>1)&3 P/V swizzle.
// (R17 (row&3): 12.6M conflicts; R22 (row>>2)&3: 12.6M — both reverted.)
// ---------------------------------------------------------------------------
__global__ __launch_bounds__(512, 4)
void attn_fused(const unsigned short* __restrict__ Qb, long sQ, int ldq,
                const unsigned short* __restrict__ K0, long sK0, int ldk0,
                const unsigned short* __restrict__ V0,
                const unsigned short* __restrict__ K1, long sK1, int ldk1,
                const unsigned short* __restrict__ V1,
                unsigned short* __restrict__ Out, long sO)
{
    __shared__ unsigned short Qs[128 * 128];  // 32 KB
    __shared__ unsigned short Ks[32 * 128];   //  8 KB
    __shared__ unsigned short Vs[256 * 32];   // 16 KB
    __shared__ unsigned short Ps[128 * 32];   //  8 KB

    const int id = blockIdx.x;            // 0..511
    const int c8 = id & 7;
    const int k  = id >> 3;               // 0..63
    const int z  = c8 * 8 + (k >> 3);     // (branch,batch)
    const int p0 = (k & 7) * 128;

    const int b  = (z < 32) ? z : z - 32;
    const unsigned short* Kp; const unsigned short* Vp; int ldk, outoff;
    if (z < 32) { Kp = K0 + (long)b * sK0; Vp = V0 + (long)b * 262144L; ldk = ldk0; outoff = 0; }
    else        { Kp = K1 + (long)b * sK1; Vp = V1 + (long)b * 262144L; ldk = ldk1; outoff = 256; }
    const unsigned short* Qp = Qb + (long)b * sQ;
    Out += (long)b * sO;

    const int tid  = threadIdx.x;
    const int lane = tid & 63;
    const int w    = tid >> 6;
    const int fr   = lane & 15;
    const int g    = lane >> 4;
    const int wp   = w >> 2;              // p-half (64 rows)
    const int wq   = w & 3;
    const int srow0 = wp * 64 + (wq >> 1) * 32;   // S: 32 rows per wave
    const int kc0   = (wq & 1) * 16;              // S: kv-col half
    const int kr    = kc0 + fr;                   // K row (0..31)
    const int wc    = wq * 64;                    // PV: c-quarter

    v4f vacc[4][4];
#pragma unroll
    for (int i = 0; i < 4; ++i)
#pragma unroll
        for (int j = 0; j < 4; ++j) vacc[i][j] = v4f{0.f, 0.f, 0.f, 0.f};
    float rp[2][4];
#pragma unroll
    for (int i = 0; i < 2; ++i)
#pragma unroll
        for (int r = 0; r < 4; ++r) rp[i][r] = 0.f;

    const int qkrow  = tid >> 4;                          // 0..31
    const int qkchk  = ((tid & 15) ^ (qkrow & 7)) * 8;
    const int vrow   = tid >> 2;                          // 0..127
    const int vchk   = ((tid & 3) ^ ((vrow >> 1) & 3)) * 8;
    const int sdst   = w * 512;

#define STAGE_Q()                                                              \
    { _Pragma("unroll")                                                        \
      for (int i = 0; i < 4; ++i)                                              \
          glds16(Qp + (long)(p0 + i * 32 + qkrow) * ldq + qkchk,               \
                 &Qs[i * 4096 + sdst]); }
#define STAGE_K(t)                                                             \
    glds16(Kp + (long)((t) * 32 + qkrow) * ldk + qkchk, &Ks[sdst]);
#define STAGE_V(t)                                                             \
    { const int kv0 = (t) * 32;                                                \
      _Pragma("unroll")                                                        \
      for (int i = 0; i < 2; ++i)                                              \
          glds16(Vp + (long)(i * 128 + vrow) * 1024 + kv0 + vchk,              \
                 &Vs[i * 4096 + sdst]); }

    STAGE_Q();
    STAGE_K(0);

    for (int t = 0; t < 32; ++t) {
        __syncthreads();              // drains Q(+K0)/K(t); PV(t-1) LDS reads done
        STAGE_V(t);                   // drained at barrier-2, covered by S+exp

        // ---- S = Q @ K^T (per wave: 32p x 16kv, K=128), exp, write P
        v4f sacc[2];
#pragma unroll
        for (int mi = 0; mi < 2; ++mi) sacc[mi] = v4f{0.f, 0.f, 0.f, 0.f};
        __builtin_amdgcn_s_setprio(1);
#pragma unroll
        for (int ks = 0; ks < 4; ++ks) {
            const v8bf kf = *reinterpret_cast<const v8bf*>(
                &Ks[kr * 128 + ((ks * 4 + g) ^ (kr & 7)) * 8]);
#pragma unroll
            for (int mi = 0; mi < 2; ++mi) {
                const int qrow = srow0 + mi * 16 + fr;
                const v8bf qf = *reinterpret_cast<const v8bf*>(
                    &Qs[qrow * 128 + ((ks * 4 + g) ^ (qrow & 7)) * 8]);
                sacc[mi] = __builtin_amdgcn_mfma_f32_16x16x32_bf16(qf, kf, sacc[mi], 0, 0, 0);
            }
        }
        __builtin_amdgcn_s_setprio(0);
#pragma unroll
        for (int mi = 0; mi < 2; ++mi)
#pragma unroll
            for (int r = 0; r < 4; ++r) {
                const float e = __expf(sacc[mi][r]);
                rp[mi][r] += e;
                const int prow = srow0 + mi * 16 + g * 4 + r;
                Ps[prow * 32 + (((kr >> 3) ^ ((prow >> 1) & 3)) << 3) + (kr & 7)] = f2u(e);
            }

        __syncthreads();              // drains V(t); Ps visible; Ks reads done
        if (t < 31) STAGE_K(t + 1);   // drained at barrier-1(t+1), covered by PV

        // ---- PV: vacc += P @ V^T (per wave: 64p x 64c, K=32 -> 1 MFMA each)
        __builtin_amdgcn_s_setprio(1);
        {
            v8bf pf[4], vf[4];
#pragma unroll
            for (int mi = 0; mi < 4; ++mi) {
                const int pr = wp * 64 + mi * 16 + fr;
                pf[mi] = *reinterpret_cast<const v8bf*>(
                    &Ps[pr * 32 + ((g ^ ((pr >> 1) & 3)) << 3)]);
            }
#pragma unroll
            for (int ni = 0; ni < 4; ++ni) {
                const int vr = wc + ni * 16 + fr;
                vf[ni] = *reinterpret_cast<const v8bf*>(
                    &Vs[vr * 32 + ((g ^ ((vr >> 1) & 3)) << 3)]);
            }
#pragma unroll
            for (int mi = 0; mi < 4; ++mi)
#pragma unroll
                for (int ni = 0; ni < 4; ++ni)
                    vacc[mi][ni] = __builtin_amdgcn_mfma_f32_16x16x32_bf16(pf[mi], vf[ni], vacc[mi][ni], 0, 0, 0);
        }
        __builtin_amdgcn_s_setprio(0);
    }
#undef STAGE_Q
#undef STAGE_K
#undef STAGE_V

    __syncthreads();
    float* red = reinterpret_cast<float*>(Ps);
#pragma unroll
    for (int mi = 0; mi < 2; ++mi)
#pragma unroll
        for (int r = 0; r < 4; ++r) {
            float v = rp[mi][r];
            v += __shfl_xor(v, 1);
            v += __shfl_xor(v, 2);
            v += __shfl_xor(v, 4);
            v += __shfl_xor(v, 8);
            if (fr == 0) red[(wq & 1) * 128 + srow0 + mi * 16 + g * 4 + r] = v;
        }
    __syncthreads();

#pragma unroll
    for (int mi = 0; mi < 4; ++mi)
#pragma unroll
        for (int r = 0; r < 4; ++r) {
            const int pl = wp * 64 + mi * 16 + g * 4 + r;
            const float inv = 1.f / (red[pl] + red[128 + pl]);
#pragma unroll
            for (int ni = 0; ni < 4; ++ni)
                Out[(long)(p0 + pl) * 512 + outoff + wc + ni * 16 + fr]
                    = f2u(vacc[mi][ni][r] * inv);
        }
}

// ---------------------------------------------------------------------------
extern "C" void kernel_launch(void* const* d_in, const int* in_sizes, int n_in,
                              void* d_out, int out_size, void* d_ws, size_t ws_size,
                              hipStream_t stream)
{
    const float* h   = (const float*)d_in[0];
    const float* m   = (const float*)d_in[1];
    const float* Wq  = (const float*)d_in[2];
    const float* bq  = (const float*)d_in[3];
    const float* Wk  = (const float*)d_in[4];
    const float* bk  = (const float*)d_in[5];
    const float* Wv  = (const float*)d_in[6];
    const float* bv  = (const float*)d_in[7];
    const float* Wk2 = (const float*)d_in[8];
    const float* bk2 = (const float*)d_in[9];
    const float* Wv2 = (const float*)d_in[10];
    const float* bv2 = (const float*)d_in[11];
    const float* Wz  = (const float*)d_in[12];
    const float* bz  = (const float*)d_in[13];
    const float* Wm  = (const float*)d_in[14];
    const float* bm  = (const float*)d_in[15];

    char* ws = (char*)d_ws;
    if (ws_size < (size_t)WS_TOTAL) return;

    unsigned short* hT  = (unsigned short*)(ws + OFF_HBT);
    unsigned short* qkh = (unsigned short*)(ws + OFF_QKH);
    unsigned short* qkm = (unsigned short*)(ws + OFF_QKM);
    unsigned short* vh  = (unsigned short*)(ws + OFF_VH);
    unsigned short* vm  = (unsigned short*)(ws + OFF_VM);
    unsigned short* zct = (unsigned short*)(ws + OFF_ZCT);
    unsigned short* wA  = (unsigned short*)(ws + OFF_W);
    float*          bA  = (float*)(ws + OFF_B);

    float* outh = (float*)d_out;
    float* outm = outh + 8388608L;

    // pack + bias-fold + transpose in ONE dispatch
    prep<<<dim3(10124), dim3(256), 0, stream>>>(
        h, m, Wq, Wk, Wv, Wk2, Wv2, Wz, Wm,
        bq, bk, bk2, bv, bv2, bz, bm, ws);

    // 5 GEMM jobs (projections, v's, Wf fold) in ONE dispatch, XCD-swizzled
    gemm_multi<<<dim3(1816), dim3(256), 0, stream>>>(ws);

    // fused attention, both branches, XCD-swizzled 1D grid (128-p tiles, KVBLK=32)
    attn_fused<<<dim3(512), dim3(512), 0, stream>>>(
        qkh, 262144L, 256,
        qkh + 128, 262144L, 256, vh,
        qkm, 131072L, 128, vm,
        zct, 524288L);

    // comb (= [zcatT | h^T] @ Wf^T + bfused) with FUSED gating epilogue
    comb_gemm<<<dim3(512), dim3(512), 0, stream>>>(
        zct, 512, hT, 256, 512,
        wA + W_F, 768, 768, bA + B_F, m, outh, outm);
}